// Round 4
// baseline (118.334 us; speedup 1.0000x reference)
//
#include <hip/hip_runtime.h>
#include <math.h>

#define BB 32
#define TT 4096
#define HH 512
#define QQS 512
#define TS 128           // chunks per batch
#define CH 32            // rows per chunk (TS*CH == TT)

#define TANH_K 2.8853900817779268f   // 2*log2(e)
#define LOG2E  1.4426950408889634f

__device__ inline float fast_exp2(float x) {
#if __has_builtin(__builtin_amdgcn_exp2f)
    return __builtin_amdgcn_exp2f(x);
#else
    return exp2f(x);
#endif
}
__device__ inline float fast_rcp(float x) {
#if __has_builtin(__builtin_amdgcn_rcpf)
    return __builtin_amdgcn_rcpf(x);
#else
    return 1.f / x;
#endif
}

__device__ inline float wave_reduce_sum(float v) {
#pragma unroll
    for (int off = 32; off > 0; off >>= 1) v += __shfl_xor(v, off, 64);
    return v;
}

// q[b][h] = sum_s query[b][s] * Wq[h][s]; one wave per (b,h)
__global__ void qproj_kernel(const float* __restrict__ query,
                             const float* __restrict__ Wq,
                             float* __restrict__ qout) {
    int wid  = (blockIdx.x * blockDim.x + threadIdx.x) >> 6;
    int lane = threadIdx.x & 63;
    int b = wid >> 9;        // / HH
    int h = wid & (HH - 1);
    const float4* qr = (const float4*)(query + (size_t)b * QQS);
    const float4* wr = (const float4*)(Wq + (size_t)h * QQS);
    float4 a0 = qr[lane],      w0 = wr[lane];
    float4 a1 = qr[lane + 64], w1 = wr[lane + 64];
    float acc = a0.x * w0.x + a0.y * w0.y + a0.z * w0.z + a0.w * w0.w
              + a1.x * w1.x + a1.y * w1.y + a1.z * w1.z + a1.w * w1.w;
    acc = wave_reduce_sum(acc);
    if (lane == 0) qout[wid] = acc;
}

// tanh contribution: th = 1 - 2*rcp(exp2(k*K + qc) + 1); p += th * w
__device__ inline float tanh_term(float k, float qc, float w, float p) {
    float e = fast_exp2(fmaf(k, TANH_K, qc));
    float r = fast_rcp(e + 1.f);
    float th = fmaf(-2.f, r, 1.f);
    return fmaf(th, w, p);
}

// Fused single-pass: per (b,chunk) block; key+value rows streamed together,
// value held in registers; one barrier for chunk max, one for ctx combine.
__global__ __launch_bounds__(256) void fused_kernel(
        const float* __restrict__ key, const float* __restrict__ value,
        const float* __restrict__ qb,  const float* __restrict__ We,
        float* __restrict__ alphas, float* __restrict__ mbuf,
        float* __restrict__ zbuf,   float* __restrict__ part) {
    __shared__ float m_lds[4];
    __shared__ float s_lds[CH];
    __shared__ float4 ctx_lds[4][HH / 4];

    int b = blockIdx.x / TS, c = blockIdx.x % TS;
    int tid = threadIdx.x, w = tid >> 6, lane = tid & 63;
    size_t row0 = (size_t)b * TT + (size_t)c * CH;

    const float4* qv = (const float4*)(qb + (size_t)b * HH);
    const float4* wv = (const float4*)We;
    float4 q0 = qv[lane], q1 = qv[lane + 64];
    float4 w0 = wv[lane], w1 = wv[lane + 64];
    q0.x *= TANH_K; q0.y *= TANH_K; q0.z *= TANH_K; q0.w *= TANH_K;
    q1.x *= TANH_K; q1.y *= TANH_K; q1.z *= TANH_K; q1.w *= TANH_K;

    const float4* kb4 = (const float4*)(key + row0 * HH);
    const float4* vb4 = (const float4*)(value + row0 * HH);

    float4 vA0, vB0, vA1, vB1, vA2, vB2, vA3, vB3;
    float4 vA4, vB4, vA5, vB5, vA6, vB6, vA7, vB7;
    float s0, s1, s2, s3, s4, s5, s6, s7;

#define ROW(J, VA, VB, SS) { \
    int r = w + 4 * (J); \
    const float4* kp = kb4 + (size_t)r * (HH / 4); \
    const float4* vp = vb4 + (size_t)r * (HH / 4); \
    VA = vp[lane]; VB = vp[lane + 64]; \
    float4 ka = kp[lane], kc = kp[lane + 64]; \
    float p = 0.f; \
    p = tanh_term(ka.x, q0.x, w0.x, p); \
    p = tanh_term(ka.y, q0.y, w0.y, p); \
    p = tanh_term(ka.z, q0.z, w0.z, p); \
    p = tanh_term(ka.w, q0.w, w0.w, p); \
    p = tanh_term(kc.x, q1.x, w1.x, p); \
    p = tanh_term(kc.y, q1.y, w1.y, p); \
    p = tanh_term(kc.z, q1.z, w1.z, p); \
    p = tanh_term(kc.w, q1.w, w1.w, p); \
    _Pragma("unroll") \
    for (int off = 32; off > 0; off >>= 1) p += __shfl_xor(p, off, 64); \
    SS = p; \
    if (lane == 0) s_lds[r] = p; \
}
    ROW(0, vA0, vB0, s0)
    ROW(1, vA1, vB1, s1)
    ROW(2, vA2, vB2, s2)
    ROW(3, vA3, vB3, s3)
    ROW(4, vA4, vB4, s4)
    ROW(5, vA5, vB5, s5)
    ROW(6, vA6, vB6, s6)
    ROW(7, vA7, vB7, s7)
#undef ROW

    float m_w = fmaxf(fmaxf(fmaxf(s0, s1), fmaxf(s2, s3)),
                      fmaxf(fmaxf(s4, s5), fmaxf(s6, s7)));
    if (lane == 0) m_lds[w] = m_w;
    __syncthreads();
    float m_c = fmaxf(fmaxf(m_lds[0], m_lds[1]), fmaxf(m_lds[2], m_lds[3]));

    float e0 = fast_exp2((s0 - m_c) * LOG2E);
    float e1 = fast_exp2((s1 - m_c) * LOG2E);
    float e2 = fast_exp2((s2 - m_c) * LOG2E);
    float e3 = fast_exp2((s3 - m_c) * LOG2E);
    float e4 = fast_exp2((s4 - m_c) * LOG2E);
    float e5 = fast_exp2((s5 - m_c) * LOG2E);
    float e6 = fast_exp2((s6 - m_c) * LOG2E);
    float e7 = fast_exp2((s7 - m_c) * LOG2E);

    float4 accA, accB;
    accA.x = e0 * vA0.x; accA.y = e0 * vA0.y; accA.z = e0 * vA0.z; accA.w = e0 * vA0.w;
    accB.x = e0 * vB0.x; accB.y = e0 * vB0.y; accB.z = e0 * vB0.z; accB.w = e0 * vB0.w;
#define ACC(E, VA, VB) \
    accA.x = fmaf(E, VA.x, accA.x); accA.y = fmaf(E, VA.y, accA.y); \
    accA.z = fmaf(E, VA.z, accA.z); accA.w = fmaf(E, VA.w, accA.w); \
    accB.x = fmaf(E, VB.x, accB.x); accB.y = fmaf(E, VB.y, accB.y); \
    accB.z = fmaf(E, VB.z, accB.z); accB.w = fmaf(E, VB.w, accB.w);
    ACC(e1, vA1, vB1) ACC(e2, vA2, vB2) ACC(e3, vA3, vB3)
    ACC(e4, vA4, vB4) ACC(e5, vA5, vB5) ACC(e6, vA6, vB6) ACC(e7, vA7, vB7)
#undef ACC

    ctx_lds[w][lane] = accA;
    ctx_lds[w][lane + 64] = accB;
    __syncthreads();

    if (tid < 128) {
        float4 t0 = ctx_lds[0][tid], t1 = ctx_lds[1][tid];
        float4 t2 = ctx_lds[2][tid], t3 = ctx_lds[3][tid];
        float4 t;
        t.x = (t0.x + t1.x) + (t2.x + t3.x);
        t.y = (t0.y + t1.y) + (t2.y + t3.y);
        t.z = (t0.z + t1.z) + (t2.z + t3.z);
        t.w = (t0.w + t1.w) + (t2.w + t3.w);
        ((float4*)(part + ((size_t)c * BB + b) * HH))[tid] = t;
    } else if (tid < 160) {
        int l = tid - 128;   // wave 2, lanes 0..31
        float e = fast_exp2((s_lds[l] - m_c) * LOG2E);
        alphas[row0 + l] = e;
        float z = e;
#pragma unroll
        for (int off = 16; off > 0; off >>= 1) z += __shfl_xor(z, off, 64);
        if (l == 0) {
            mbuf[b * TS + c] = m_c;
            zbuf[b * TS + c] = z;
        }
    }
}

// Finalize: blocks 0..31 -> rescale alphas in place; blocks 32..95 -> context
__global__ void finalize_kernel(const float* __restrict__ mbuf,
                                const float* __restrict__ zbuf,
                                const float* __restrict__ part,
                                float* __restrict__ alphas,
                                float* __restrict__ ctx) {
    __shared__ float red[8];
    __shared__ float scale[TS];
    int tid = threadIdx.x, lane = tid & 63, w = tid >> 6;
    int b = (blockIdx.x < BB) ? blockIdx.x : ((blockIdx.x - BB) >> 1);

    float m_l = -1e30f, z_l = 0.f;
    if (tid < TS) { m_l = mbuf[b * TS + tid]; z_l = zbuf[b * TS + tid]; }
    float m = m_l;
#pragma unroll
    for (int off = 32; off > 0; off >>= 1) m = fmaxf(m, __shfl_xor(m, off, 64));
    if (lane == 0) red[w] = m;
    __syncthreads();
    float M = fmaxf(fmaxf(red[0], red[1]), fmaxf(red[2], red[3]));
    float ez = (tid < TS) ? __expf(m_l - M) * z_l : 0.f;
#pragma unroll
    for (int off = 32; off > 0; off >>= 1) ez += __shfl_xor(ez, off, 64);
    if (lane == 0) red[4 + w] = ez;
    __syncthreads();
    float Z = (red[4] + red[5]) + (red[6] + red[7]);
    if (tid < TS) scale[tid] = __expf(m_l - M) / Z;
    __syncthreads();

    if (blockIdx.x < BB) {
        float4* ap = (float4*)(alphas + (size_t)b * TT);
#pragma unroll
        for (int i = 0; i < 4; ++i) {
            int idx = tid + i * 256;
            float4 a = ap[idx];
            float s = scale[idx >> 3];   // 8 float4 = 32 floats per chunk
            a.x *= s; a.y *= s; a.z *= s; a.w *= s;
            ap[idx] = a;
        }
    } else {
        int d = ((blockIdx.x - BB) & 1) * 256 + tid;
        float s = 0.f;
#pragma unroll 8
        for (int c2 = 0; c2 < TS; ++c2)
            s += scale[c2] * part[((size_t)c2 * BB + b) * HH + d];
        ctx[(size_t)b * HH + d] = s;
    }
}

extern "C" void kernel_launch(void* const* d_in, const int* in_sizes, int n_in,
                              void* d_out, int out_size, void* d_ws, size_t ws_size,
                              hipStream_t stream) {
    const float* query = (const float*)d_in[0];
    const float* key   = (const float*)d_in[1];
    const float* value = (const float*)d_in[2];
    // d_in[3] = mask (unused by reference forward)
    const float* Wq    = (const float*)d_in[4];
    const float* We    = (const float*)d_in[5];

    float* ctx    = (float*)d_out;            // [B,1,H]
    float* alphas = (float*)d_out + BB * HH;  // [B,T]

    float* qbuf   = (float*)d_ws;                    // B*H
    float* mbuf   = qbuf + BB * HH;                  // B*TS
    float* zbuf   = mbuf + BB * TS;                  // B*TS
    float* part   = zbuf + BB * TS;                  // TS*B*H = 8 MiB

    qproj_kernel<<<(BB * HH) / 4, 256, 0, stream>>>(query, Wq, qbuf);
    fused_kernel<<<BB * TS, 256, 0, stream>>>(key, value, qbuf, We, alphas, mbuf, zbuf, part);
    finalize_kernel<<<BB + 2 * BB, 256, 0, stream>>>(mbuf, zbuf, part, alphas, ctx);
}

// Round 5
// 114.716 us; speedup vs baseline: 1.0315x; 1.0315x over previous
//
#include <hip/hip_runtime.h>
#include <math.h>

#define BB 32
#define TT 4096
#define HH 512
#define QQS 512
#define TS 64            // chunks per batch
#define CH 64            // rows per chunk (TS*CH == TT)

#define TANH_K 2.8853900817779268f   // 2*log2(e)
#define LOG2E  1.4426950408889634f

__device__ inline float fast_exp2(float x) {
#if __has_builtin(__builtin_amdgcn_exp2f)
    return __builtin_amdgcn_exp2f(x);
#else
    return exp2f(x);
#endif
}
__device__ inline float fast_rcp(float x) {
#if __has_builtin(__builtin_amdgcn_rcpf)
    return __builtin_amdgcn_rcpf(x);
#else
    return 1.f / x;
#endif
}

__device__ inline float wave_reduce_sum(float v) {
#pragma unroll
    for (int off = 32; off > 0; off >>= 1) v += __shfl_xor(v, off, 64);
    return v;
}

// q[b][h] = sum_s query[b][s] * Wq[h][s]; one wave per (b,h)
__global__ void qproj_kernel(const float* __restrict__ query,
                             const float* __restrict__ Wq,
                             float* __restrict__ qout) {
    int wid  = (blockIdx.x * blockDim.x + threadIdx.x) >> 6;
    int lane = threadIdx.x & 63;
    int b = wid >> 9;        // / HH
    int h = wid & (HH - 1);
    const float4* qr = (const float4*)(query + (size_t)b * QQS);
    const float4* wr = (const float4*)(Wq + (size_t)h * QQS);
    float4 a0 = qr[lane],      w0 = wr[lane];
    float4 a1 = qr[lane + 64], w1 = wr[lane + 64];
    float acc = a0.x * w0.x + a0.y * w0.y + a0.z * w0.z + a0.w * w0.w
              + a1.x * w1.x + a1.y * w1.y + a1.z * w1.z + a1.w * w1.w;
    acc = wave_reduce_sum(acc);
    if (lane == 0) qout[wid] = acc;
}

// tanh contribution: th = 1 - 2*rcp(exp2(k*K + qc) + 1); p += th * w
__device__ inline float tanh_term(float k, float qc, float w, float p) {
    float e = fast_exp2(fmaf(k, TANH_K, qc));
    float r = fast_rcp(e + 1.f);
    float th = fmaf(-2.f, r, 1.f);
    return fmaf(th, w, p);
}

// Fused, no-max online pass: per (b,chunk) block; per row pair: load k+v,
// score, e=exp(s) immediately, FMA into register ctx. One barrier total.
__global__ __launch_bounds__(256) void fused_kernel(
        const float* __restrict__ key, const float* __restrict__ value,
        const float* __restrict__ qb,  const float* __restrict__ We,
        float* __restrict__ alphas, float* __restrict__ zbuf,
        float* __restrict__ part) {
    __shared__ float e_lds[CH];
    __shared__ float4 ctx_lds[4][HH / 4];

    int b = blockIdx.x / TS, c = blockIdx.x % TS;
    int tid = threadIdx.x, w = tid >> 6, lane = tid & 63;
    size_t row0 = (size_t)b * TT + (size_t)c * CH;

    const float4* qv = (const float4*)(qb + (size_t)b * HH);
    const float4* wv = (const float4*)We;
    float4 q0 = qv[lane], q1 = qv[lane + 64];
    float4 w0 = wv[lane], w1 = wv[lane + 64];
    q0.x *= TANH_K; q0.y *= TANH_K; q0.z *= TANH_K; q0.w *= TANH_K;
    q1.x *= TANH_K; q1.y *= TANH_K; q1.z *= TANH_K; q1.w *= TANH_K;

    const float4* kb4 = (const float4*)(key + row0 * HH);
    const float4* vb4 = (const float4*)(value + row0 * HH);

    float4 accA = make_float4(0.f, 0.f, 0.f, 0.f);
    float4 accB = make_float4(0.f, 0.f, 0.f, 0.f);

    // wave w owns rows {w, w+4, ..., w+60}; 2 rows per iteration
    for (int j = 0; j < 16; j += 2) {
        int r0 = w + 4 * j, r1 = r0 + 4;
        const float4* kp0 = kb4 + (size_t)r0 * (HH / 4);
        const float4* kp1 = kb4 + (size_t)r1 * (HH / 4);
        const float4* vp0 = vb4 + (size_t)r0 * (HH / 4);
        const float4* vp1 = vb4 + (size_t)r1 * (HH / 4);
        float4 ka0 = kp0[lane], kc0 = kp0[lane + 64];
        float4 ka1 = kp1[lane], kc1 = kp1[lane + 64];
        float4 va0 = vp0[lane], vc0 = vp0[lane + 64];
        float4 va1 = vp1[lane], vc1 = vp1[lane + 64];

        float p0 = 0.f, p1 = 0.f;
        p0 = tanh_term(ka0.x, q0.x, w0.x, p0);
        p0 = tanh_term(ka0.y, q0.y, w0.y, p0);
        p0 = tanh_term(ka0.z, q0.z, w0.z, p0);
        p0 = tanh_term(ka0.w, q0.w, w0.w, p0);
        p0 = tanh_term(kc0.x, q1.x, w1.x, p0);
        p0 = tanh_term(kc0.y, q1.y, w1.y, p0);
        p0 = tanh_term(kc0.z, q1.z, w1.z, p0);
        p0 = tanh_term(kc0.w, q1.w, w1.w, p0);
        p1 = tanh_term(ka1.x, q0.x, w0.x, p1);
        p1 = tanh_term(ka1.y, q0.y, w0.y, p1);
        p1 = tanh_term(ka1.z, q0.z, w0.z, p1);
        p1 = tanh_term(ka1.w, q0.w, w0.w, p1);
        p1 = tanh_term(kc1.x, q1.x, w1.x, p1);
        p1 = tanh_term(kc1.y, q1.y, w1.y, p1);
        p1 = tanh_term(kc1.z, q1.z, w1.z, p1);
        p1 = tanh_term(kc1.w, q1.w, w1.w, p1);

        // paired reduce: lanes<32 -> sum(p0), lanes>=32 -> sum(p1)
        float a0 = __shfl_xor(p0, 32, 64);
        float a1 = __shfl_xor(p1, 32, 64);
        float ws = (lane < 32) ? (p0 + a0) : (p1 + a1);
#pragma unroll
        for (int off = 16; off > 0; off >>= 1) ws += __shfl_xor(ws, off, 64);
        float s0 = __shfl(ws, 0, 64);
        float s1 = __shfl(ws, 32, 64);

        float e0 = fast_exp2(s0 * LOG2E);
        float e1 = fast_exp2(s1 * LOG2E);
        if (lane == 0) { e_lds[r0] = e0; e_lds[r1] = e1; }

        accA.x = fmaf(e0, va0.x, accA.x); accA.y = fmaf(e0, va0.y, accA.y);
        accA.z = fmaf(e0, va0.z, accA.z); accA.w = fmaf(e0, va0.w, accA.w);
        accB.x = fmaf(e0, vc0.x, accB.x); accB.y = fmaf(e0, vc0.y, accB.y);
        accB.z = fmaf(e0, vc0.z, accB.z); accB.w = fmaf(e0, vc0.w, accB.w);
        accA.x = fmaf(e1, va1.x, accA.x); accA.y = fmaf(e1, va1.y, accA.y);
        accA.z = fmaf(e1, va1.z, accA.z); accA.w = fmaf(e1, va1.w, accA.w);
        accB.x = fmaf(e1, vc1.x, accB.x); accB.y = fmaf(e1, vc1.y, accB.y);
        accB.z = fmaf(e1, vc1.z, accB.z); accB.w = fmaf(e1, vc1.w, accB.w);
    }

    ctx_lds[w][lane] = accA;
    ctx_lds[w][lane + 64] = accB;
    __syncthreads();

    if (tid < 128) {
        float4 t0 = ctx_lds[0][tid], t1 = ctx_lds[1][tid];
        float4 t2 = ctx_lds[2][tid], t3 = ctx_lds[3][tid];
        float4 t;
        t.x = (t0.x + t1.x) + (t2.x + t3.x);
        t.y = (t0.y + t1.y) + (t2.y + t3.y);
        t.z = (t0.z + t1.z) + (t2.z + t3.z);
        t.w = (t0.w + t1.w) + (t2.w + t3.w);
        ((float4*)(part + ((size_t)c * BB + b) * HH))[tid] = t;
    } else if (tid < 192) {
        int l = tid - 128;   // wave 2, full 64 lanes
        float e = e_lds[l];
        float z = wave_reduce_sum(e);
        if (l == 0) zbuf[b * TS + c] = z;
        if (l < CH / 4)
            ((float4*)(alphas + row0))[l] = ((const float4*)e_lds)[l];
    }
}

// Finalize: blocks 0..31 -> rescale alphas in place; blocks 32..95 -> context
__global__ void finalize_kernel(const float* __restrict__ zbuf,
                                const float* __restrict__ part,
                                float* __restrict__ alphas,
                                float* __restrict__ ctx) {
    int tid = threadIdx.x, lane = tid & 63;
    int b = (blockIdx.x < BB) ? blockIdx.x : ((blockIdx.x - BB) >> 1);

    // every wave redundantly reduces the 64 chunk-sums (fixed order)
    float z = zbuf[b * TS + lane];
    float Z = wave_reduce_sum(z);
    float invZ = fast_rcp(Z);

    if (blockIdx.x < BB) {
        float4* ap = (float4*)(alphas + (size_t)b * TT);
#pragma unroll
        for (int i = 0; i < 4; ++i) {
            int idx = tid + i * 256;
            float4 a = ap[idx];
            a.x *= invZ; a.y *= invZ; a.z *= invZ; a.w *= invZ;
            ap[idx] = a;
        }
    } else {
        int d = ((blockIdx.x - BB) & 1) * 256 + tid;
        float s = 0.f;
#pragma unroll 8
        for (int c2 = 0; c2 < TS; ++c2)
            s += part[((size_t)c2 * BB + b) * HH + d];
        ctx[(size_t)b * HH + d] = s * invZ;
    }
}

extern "C" void kernel_launch(void* const* d_in, const int* in_sizes, int n_in,
                              void* d_out, int out_size, void* d_ws, size_t ws_size,
                              hipStream_t stream) {
    const float* query = (const float*)d_in[0];
    const float* key   = (const float*)d_in[1];
    const float* value = (const float*)d_in[2];
    // d_in[3] = mask (unused by reference forward)
    const float* Wq    = (const float*)d_in[4];
    const float* We    = (const float*)d_in[5];

    float* ctx    = (float*)d_out;            // [B,1,H]
    float* alphas = (float*)d_out + BB * HH;  // [B,T]

    float* qbuf   = (float*)d_ws;                    // B*H
    float* zbuf   = qbuf + BB * HH;                  // B*TS
    float* part   = zbuf + BB * TS;                  // TS*B*H = 4 MiB

    qproj_kernel<<<(BB * HH) / 4, 256, 0, stream>>>(query, Wq, qbuf);
    fused_kernel<<<BB * TS, 256, 0, stream>>>(key, value, qbuf, We, alphas, zbuf, part);
    finalize_kernel<<<BB + 2 * BB, 256, 0, stream>>>(zbuf, part, alphas, ctx);
}